// Round 1
// baseline (279.994 us; speedup 1.0000x reference)
//
#include <hip/hip_runtime.h>

#define S_LEN 2048
#define HD 64
#define KVB 32
#define NT (S_LEN / KVB)   // 64 kv tiles

typedef float f32x4 __attribute__((ext_vector_type(4)));
typedef short s16x8 __attribute__((ext_vector_type(8)));
typedef int   i32x4 __attribute__((ext_vector_type(4)));

__device__ __forceinline__ short f2bf(float f) {
    unsigned u = __builtin_bit_cast(unsigned, f);
    unsigned r = (u + 0x7FFFu + ((u >> 16) & 1u)) >> 16;
    return (short)(unsigned short)r;
}

__device__ __forceinline__ int pack2bf(float a, float b) {
    unsigned lo = (unsigned short)f2bf(a);
    unsigned hi = (unsigned short)f2bf(b);
    return (int)(lo | (hi << 16));
}

__global__ __launch_bounds__(256)
void attn_fwd(const float* __restrict__ Qg, const float* __restrict__ Kg,
              const float* __restrict__ Vg, const int* __restrict__ Mg,
              float* __restrict__ Og) {
    // K tile: [32 keys][72 d] bf16 (padded stride); V^T tile: [64 d][40 keys] bf16
    __shared__ __align__(16) short Klds[32 * 72];
    __shared__ __align__(16) short Vtlds[64 * 40];
    __shared__ float Mlds[32];

    const int t    = threadIdx.x;
    const int lane = t & 63;
    const int wid  = t >> 6;
    const int c    = lane & 15;   // 16-dim index (q in S^T, d-col in O)
    const int g    = lane >> 4;   // lane group 0..3

    const int bh   = blockIdx.x >> 4;         // 0..63
    const int qblk = (blockIdx.x & 15) * 128; // q-block start
    const int b    = bh >> 4;                 // batch (H=16)

    const size_t base = (size_t)bh * S_LEN * HD;

    // ---- Q fragments (pre-scaled by 1/sqrt(64)=0.125): 2 q-tiles x 2 k-steps
    s16x8 qf[2][2];
    const int qrow0 = qblk + wid * 32;
#pragma unroll
    for (int qt = 0; qt < 2; ++qt) {
#pragma unroll
      for (int ks = 0; ks < 2; ++ks) {
        const float* qp = Qg + base + (size_t)(qrow0 + qt*16 + c) * HD + 8*g + 32*ks;
        float4 a  = *(const float4*)qp;
        float4 bq = *(const float4*)(qp + 4);
        s16x8 f;
        f[0]=f2bf(a.x*0.125f);  f[1]=f2bf(a.y*0.125f);  f[2]=f2bf(a.z*0.125f);  f[3]=f2bf(a.w*0.125f);
        f[4]=f2bf(bq.x*0.125f); f[5]=f2bf(bq.y*0.125f); f[6]=f2bf(bq.z*0.125f); f[7]=f2bf(bq.w*0.125f);
        qf[qt][ks] = f;
      }
    }

    // ---- staging assignment: thread -> (key, 8 d-elems)
    const int skey = t & 31;
    const int sd   = (t >> 5) * 8;
    const float* kstage = Kg + base + (size_t)skey * HD + sd;
    const float* vstage = Vg + base + (size_t)skey * HD + sd;

    float4 kr0, kr1, vr0, vr1; float mreg = 0.f;
    kr0 = *(const float4*)(kstage);
    kr1 = *(const float4*)(kstage + 4);
    vr0 = *(const float4*)(vstage);
    vr1 = *(const float4*)(vstage + 4);
    if (t < 32) mreg = (float)Mg[(size_t)b * S_LEN + t];

    f32x4 acc[2][4];
#pragma unroll
    for (int qt=0;qt<2;++qt)
#pragma unroll
      for(int dt=0;dt<4;++dt) acc[qt][dt] = (f32x4){0.f,0.f,0.f,0.f};
    float mrun[2] = {-1e30f, -1e30f};
    float lrun[2] = {0.f, 0.f};

    for (int it = 0; it < NT; ++it) {
      __syncthreads();   // previous tile's LDS reads complete
      // ---- write staged tile to LDS (bf16)
      {
        s16x8 kb;
        kb[0]=f2bf(kr0.x); kb[1]=f2bf(kr0.y); kb[2]=f2bf(kr0.z); kb[3]=f2bf(kr0.w);
        kb[4]=f2bf(kr1.x); kb[5]=f2bf(kr1.y); kb[6]=f2bf(kr1.z); kb[7]=f2bf(kr1.w);
        *(s16x8*)&Klds[skey*72 + sd] = kb;
        Vtlds[(sd+0)*40 + skey] = f2bf(vr0.x);
        Vtlds[(sd+1)*40 + skey] = f2bf(vr0.y);
        Vtlds[(sd+2)*40 + skey] = f2bf(vr0.z);
        Vtlds[(sd+3)*40 + skey] = f2bf(vr0.w);
        Vtlds[(sd+4)*40 + skey] = f2bf(vr1.x);
        Vtlds[(sd+5)*40 + skey] = f2bf(vr1.y);
        Vtlds[(sd+6)*40 + skey] = f2bf(vr1.z);
        Vtlds[(sd+7)*40 + skey] = f2bf(vr1.w);
        if (t < 32) Mlds[t] = mreg;
      }
      __syncthreads();

      // ---- read fragments from LDS
      s16x8 kf[2][2];
#pragma unroll
      for (int tile=0; tile<2; ++tile)
#pragma unroll
        for (int ks=0; ks<2; ++ks)
          kf[tile][ks] = *(const s16x8*)&Klds[(16*tile + c)*72 + 8*g + 32*ks];
      s16x8 vf[4];
#pragma unroll
      for (int dt=0; dt<4; ++dt)
        vf[dt] = *(const s16x8*)&Vtlds[(c + 16*dt)*40 + 8*g];
      f32x4 mv0 = *(const f32x4*)&Mlds[4*g];
      f32x4 mv1 = *(const f32x4*)&Mlds[16 + 4*g];

      // ---- prefetch next tile global->reg (latency hides under compute)
      if (it + 1 < NT) {
        const float* kp = kstage + (size_t)(it+1)*KVB*HD;
        const float* vp = vstage + (size_t)(it+1)*KVB*HD;
        kr0 = *(const float4*)kp; kr1 = *(const float4*)(kp+4);
        vr0 = *(const float4*)vp; vr1 = *(const float4*)(vp+4);
        if (t < 32) mreg = (float)Mg[(size_t)b*S_LEN + (it+1)*KVB + t];
      }

#pragma unroll
      for (int qt=0; qt<2; ++qt) {
        // S^T tiles: rows=keys (16t+4g+jr), cols=q (c). A=K, B=Q.
        f32x4 z = (f32x4){0.f,0.f,0.f,0.f};
        f32x4 st0 = __builtin_amdgcn_mfma_f32_16x16x32_bf16(kf[0][0], qf[qt][0], z, 0,0,0);
        st0       = __builtin_amdgcn_mfma_f32_16x16x32_bf16(kf[0][1], qf[qt][1], st0, 0,0,0);
        f32x4 st1 = __builtin_amdgcn_mfma_f32_16x16x32_bf16(kf[1][0], qf[qt][0], z, 0,0,0);
        st1       = __builtin_amdgcn_mfma_f32_16x16x32_bf16(kf[1][1], qf[qt][1], st1, 0,0,0);

        // row(=q) max: 8 local + xor-16/32 across lane groups
        float tmax = fmaxf(fmaxf(fmaxf(st0[0],st0[1]),fmaxf(st0[2],st0[3])),
                           fmaxf(fmaxf(st1[0],st1[1]),fmaxf(st1[2],st1[3])));
        tmax = fmaxf(tmax, __shfl_xor(tmax, 16, 64));
        tmax = fmaxf(tmax, __shfl_xor(tmax, 32, 64));
        float mnew  = fmaxf(mrun[qt], tmax);
        float alpha = __expf(mrun[qt] - mnew);
        mrun[qt] = mnew;

        float p[8];
#pragma unroll
        for (int jr=0;jr<4;++jr) p[jr]   = __expf(st0[jr]-mnew) * mv0[jr];
#pragma unroll
        for (int jr=0;jr<4;++jr) p[4+jr] = __expf(st1[jr]-mnew) * mv1[jr];

        float rs = ((p[0]+p[1])+(p[2]+p[3])) + ((p[4]+p[5])+(p[6]+p[7]));
        rs += __shfl_xor(rs, 16, 64);
        rs += __shfl_xor(rs, 32, 64);
        lrun[qt] = lrun[qt]*alpha + rs;

        // rescale O by alpha (alpha lives at q=c; O rows are q=4g+jr -> shuffle)
#pragma unroll
        for (int jr=0;jr<4;++jr) {
          float aj = __shfl(alpha, 4*g + jr, 64);
#pragma unroll
          for (int dt=0;dt<4;++dt) acc[qt][dt][jr] *= aj;
        }

        // pack P to bf16 pairs, repack S^T-layout -> A-fragment layout
        int w0[2], w1[2];
        w0[0] = pack2bf(p[0], p[1]); w0[1] = pack2bf(p[2], p[3]);
        w1[0] = pack2bf(p[4], p[5]); w1[1] = pack2bf(p[6], p[7]);
        i32x4 pfi;
#pragma unroll
        for (int tt=0; tt<4; ++tt) {
          int src = c + 16*(2*(g&1) + (tt>>1));
          int a0 = __shfl(w0[tt&1], src, 64);
          int a1 = __shfl(w1[tt&1], src, 64);
          pfi[tt] = (g >= 2) ? a1 : a0;
        }
        s16x8 pf = __builtin_bit_cast(s16x8, pfi);

        // O += P @ V  (A=P frag, B=V from Vt: contiguous b128 reads)
#pragma unroll
        for (int dt=0;dt<4;++dt)
          acc[qt][dt] = __builtin_amdgcn_mfma_f32_16x16x32_bf16(pf, vf[dt], acc[qt][dt], 0,0,0);
      }
    }

    // ---- epilogue: normalize by row-sum and store fp32
#pragma unroll
    for (int qt=0;qt<2;++qt) {
#pragma unroll
      for (int jr=0;jr<4;++jr) {
        float lj   = __shfl(lrun[qt], 4*g + jr, 64);
        float linv = 1.0f / lj;
#pragma unroll
        for (int dt=0;dt<4;++dt) {
          int qrow = qrow0 + qt*16 + 4*g + jr;
          Og[base + (size_t)qrow * HD + c + 16*dt] = acc[qt][dt][jr] * linv;
        }
      }
    }
}

extern "C" void kernel_launch(void* const* d_in, const int* in_sizes, int n_in,
                              void* d_out, int out_size, void* d_ws, size_t ws_size,
                              hipStream_t stream) {
    const float* Q = (const float*)d_in[0];
    const float* K = (const float*)d_in[1];
    const float* V = (const float*)d_in[2];
    const int*   M = (const int*)d_in[3];
    float* O = (float*)d_out;
    dim3 grid(1024), block(256);
    hipLaunchKernelGGL(attn_fwd, grid, block, 0, stream, Q, K, V, M, O);
}

// Round 2
// 126.577 us; speedup vs baseline: 2.2120x; 2.2120x over previous
//
#include <hip/hip_runtime.h>

#define S_LEN 2048
#define HD 64
#define KVB 32
#define NT (S_LEN / KVB)   // 64 kv tiles

typedef float f32x4  __attribute__((ext_vector_type(4)));
typedef float f32x16 __attribute__((ext_vector_type(16)));
typedef short bf16x8 __attribute__((ext_vector_type(8)));
typedef int   i32x2  __attribute__((ext_vector_type(2)));
typedef int   i32x4  __attribute__((ext_vector_type(4)));

#define SQ_SCALE 0.18033688011112042f   // 0.125 * log2(e)
#define MASK_B  (-1442695.040888963f)   // -1e6 * log2(e)
#define THR 10.0f

static __device__ __forceinline__ int cvt_pk(float lo, float hi) {
  int r;
  asm("v_cvt_pk_bf16_f32 %0, %1, %2" : "=v"(r) : "v"(lo), "v"(hi));
  return r;
}
static __device__ __forceinline__ float exp2v(float x) {
  float r;
  asm("v_exp_f32 %0, %1" : "=v"(r) : "v"(x));
  return r;
}
static __device__ __forceinline__ void swap32(int &a, int &b) {
  asm("v_permlane32_swap_b32 %0, %1" : "+v"(a), "+v"(b));
}

__global__ __launch_bounds__(256, 4)
void attn_fwd(const float* __restrict__ Qg, const float* __restrict__ Kg,
              const float* __restrict__ Vg, const int* __restrict__ Mg,
              float* __restrict__ Og) {
  // K tile: [32 keys][72 d] bf16; V^T tile: [64 d][40 keys] bf16; mask bias[32] f32
  __shared__ __align__(16) short Klds[2][32 * 72];
  __shared__ __align__(16) short Vtld[2][64 * 40];
  __shared__ __align__(16) float MB[2][32];

  const int t    = threadIdx.x;
  const int lane = t & 63;
  const int wid  = t >> 6;
  const int c    = lane & 31;   // q column (and d-row for V^T A-frag)
  const int hi   = lane >> 5;   // lane half

  const int bh   = blockIdx.x >> 4;         // 0..63
  const int qblk = (blockIdx.x & 15) * 128; // 128 q rows per block
  const int b    = bh >> 4;                 // batch (H=16)
  const size_t base = (size_t)bh * S_LEN * HD;
  const int qbase = qblk + wid * 32;        // this wave's 32 q rows

  // ---- Q fragment (B-operand of QK^T): lane holds Q[qbase+c][16s+8hi .. +7]
  bf16x8 qf[4];
#pragma unroll
  for (int s = 0; s < 4; ++s) {
    const float* qp = Qg + base + (size_t)(qbase + c) * HD + 16*s + 8*hi;
    float4 x0 = *(const float4*)qp;
    float4 x1 = *(const float4*)(qp + 4);
    i32x4 w;
    w[0] = cvt_pk(x0.x*SQ_SCALE, x0.y*SQ_SCALE);
    w[1] = cvt_pk(x0.z*SQ_SCALE, x0.w*SQ_SCALE);
    w[2] = cvt_pk(x1.x*SQ_SCALE, x1.y*SQ_SCALE);
    w[3] = cvt_pk(x1.z*SQ_SCALE, x1.w*SQ_SCALE);
    qf[s] = __builtin_bit_cast(bf16x8, w);
  }

  // ---- staging roles
  const int kkey = t & 31, kdg = t >> 5;   // K: (key, 8-d group)
  const int vd   = t & 63, vkg = t >> 6;   // V: (d, 4-key group)
  const float* kbase = Kg + base + (size_t)kkey * HD + 8*kdg;
  const float* vbase = Vg + base + vd + (size_t)(4*vkg) * HD;
  const int*   mbase = Mg + (size_t)b * S_LEN;

  float kr[8], vr[8]; float mbias = 0.f;

  auto LOADT = [&](int it) {
    const float* kp = kbase + (size_t)it * KVB * HD;
    *(float4*)&kr[0] = *(const float4*)kp;
    *(float4*)&kr[4] = *(const float4*)(kp + 4);
    const float* vp = vbase + (size_t)it * KVB * HD;
#pragma unroll
    for (int i = 0; i < 2; ++i)
#pragma unroll
      for (int j = 0; j < 4; ++j)
        vr[i*4+j] = vp[(16*i + j) * HD];
    if (t < 32) {
      int m = mbase[it * KVB + t];
      mbias = m ? 0.f : MASK_B;
    }
  };
  auto STORET = [&](int bf) {
    i32x4 kw;
    kw[0] = cvt_pk(kr[0], kr[1]); kw[1] = cvt_pk(kr[2], kr[3]);
    kw[2] = cvt_pk(kr[4], kr[5]); kw[3] = cvt_pk(kr[6], kr[7]);
    *(i32x4*)&Klds[bf][kkey*72 + 8*kdg] = kw;
    i32x2 va, vb;
    va[0] = cvt_pk(vr[0], vr[1]); va[1] = cvt_pk(vr[2], vr[3]);
    vb[0] = cvt_pk(vr[4], vr[5]); vb[1] = cvt_pk(vr[6], vr[7]);
    *(i32x2*)&Vtld[bf][vd*40 + 4*vkg]      = va;
    *(i32x2*)&Vtld[bf][vd*40 + 16 + 4*vkg] = vb;
    if (t < 32) MB[bf][t] = mbias;
  };

  f32x16 acc0 = {};  // O^T rows d=0..31
  f32x16 acc1 = {};  // O^T rows d=32..63
  float mrun = -1e30f, lrun = 0.f;

  LOADT(0); STORET(0); LOADT(1);
  __syncthreads();

  for (int it = 0; it < NT; ++it) {
    if (it + 1 < NT) STORET((it + 1) & 1);
    if (it + 2 < NT) LOADT(it + 2);
    const int cur = it & 1;

    // ---- S^T = K · Q^T  (rows=keys, cols=q)
    f32x16 S = {};
#pragma unroll
    for (int s = 0; s < 4; ++s) {
      bf16x8 kf = *(const bf16x8*)&Klds[cur][c*72 + 16*s + 8*hi];
      S = __builtin_amdgcn_mfma_f32_32x32x16_bf16(kf, qf[s], S, 0, 0, 0);
    }

    f32x4 bias4[4];
#pragma unroll
    for (int m = 0; m < 4; ++m)
      bias4[m] = *(const f32x4*)&MB[cur][8*m + 4*hi];

    // sb[r]: logit2 for key (r&3)+8*(r>>2)+4*hi, q=c
    float sb[16];
#pragma unroll
    for (int r = 0; r < 16; ++r)
      sb[r] = S[r] + bias4[r >> 2][r & 3];

    // row max over this tile's 32 keys
    float mx[8];
#pragma unroll
    for (int r = 0; r < 8; ++r) mx[r] = fmaxf(sb[r], sb[r+8]);
#pragma unroll
    for (int r = 0; r < 4; ++r) mx[r] = fmaxf(mx[r], mx[r+4]);
    float tmax = fmaxf(fmaxf(mx[0], mx[1]), fmaxf(mx[2], mx[3]));
    tmax = fmaxf(tmax, __shfl_xor(tmax, 32, 64));

    // defer-max: rescale only when the running max grows by > THR
    if (!__all(tmax <= mrun + THR)) {
      float mnew = fmaxf(mrun, tmax);
      float al = exp2v(mrun - mnew);
      acc0 *= al; acc1 *= al;
      lrun *= al; mrun = mnew;
    }

    // p = exp2(logit2 - m) (reuse sb)
#pragma unroll
    for (int r = 0; r < 16; ++r) sb[r] = exp2v(sb[r] - mrun);

    float sm[8];
#pragma unroll
    for (int r = 0; r < 8; ++r) sm[r] = sb[r] + sb[r+8];
#pragma unroll
    for (int r = 0; r < 4; ++r) sm[r] = sm[r] + sm[r+4];
    float rs = (sm[0] + sm[1]) + (sm[2] + sm[3]);
    rs += __shfl_xor(rs, 32, 64);
    lrun += rs;

    // pack P to bf16; permlane32_swap redistributes into B-fragment order
    int w[8];
#pragma unroll
    for (int m = 0; m < 8; ++m) w[m] = cvt_pk(sb[2*m], sb[2*m+1]);
    swap32(w[0], w[2]); swap32(w[1], w[3]);
    swap32(w[4], w[6]); swap32(w[5], w[7]);
    i32x4 pw0 = {w[0], w[1], w[2], w[3]};   // keys 0..15
    i32x4 pw1 = {w[4], w[5], w[6], w[7]};   // keys 16..31
    bf16x8 pb0 = __builtin_bit_cast(bf16x8, pw0);
    bf16x8 pb1 = __builtin_bit_cast(bf16x8, pw1);

    // ---- O^T += V^T · P^T
    {
      bf16x8 v00 = *(const bf16x8*)&Vtld[cur][(c     )*40      + 8*hi];
      bf16x8 v01 = *(const bf16x8*)&Vtld[cur][(c     )*40 + 16 + 8*hi];
      bf16x8 v10 = *(const bf16x8*)&Vtld[cur][(c + 32)*40      + 8*hi];
      bf16x8 v11 = *(const bf16x8*)&Vtld[cur][(c + 32)*40 + 16 + 8*hi];
      acc0 = __builtin_amdgcn_mfma_f32_32x32x16_bf16(v00, pb0, acc0, 0, 0, 0);
      acc0 = __builtin_amdgcn_mfma_f32_32x32x16_bf16(v01, pb1, acc0, 0, 0, 0);
      acc1 = __builtin_amdgcn_mfma_f32_32x32x16_bf16(v10, pb0, acc1, 0, 0, 0);
      acc1 = __builtin_amdgcn_mfma_f32_32x32x16_bf16(v11, pb1, acc1, 0, 0, 0);
    }

    __syncthreads();
  }

  // ---- epilogue: O[q][d] = O^T/l ; all lane-local, float4 stores
  const float linv = 1.0f / lrun;
  float* op = Og + base + (size_t)(qbase + c) * HD + 4*hi;
#pragma unroll
  for (int m = 0; m < 4; ++m) {
    f32x4 o0, o1;
#pragma unroll
    for (int j = 0; j < 4; ++j) {
      o0[j] = acc0[4*m + j] * linv;
      o1[j] = acc1[4*m + j] * linv;
    }
    *(f32x4*)(op + 8*m)      = o0;   // d = 8m+4hi .. +3
    *(f32x4*)(op + 32 + 8*m) = o1;   // d = 32+8m+4hi .. +3
  }
}

extern "C" void kernel_launch(void* const* d_in, const int* in_sizes, int n_in,
                              void* d_out, int out_size, void* d_ws, size_t ws_size,
                              hipStream_t stream) {
    const float* Q = (const float*)d_in[0];
    const float* K = (const float*)d_in[1];
    const float* V = (const float*)d_in[2];
    const int*   M = (const int*)d_in[3];
    float* O = (float*)d_out;
    dim3 grid(1024), block(256);
    hipLaunchKernelGGL(attn_fwd, grid, block, 0, stream, Q, K, V, M, O);
}

// Round 4
// 120.962 us; speedup vs baseline: 2.3147x; 1.0464x over previous
//
#include <hip/hip_runtime.h>

#define S_LEN 2048
#define HD 64
#define KVB 32
#define NT (S_LEN / KVB)   // 64 kv tiles

typedef float f32x4  __attribute__((ext_vector_type(4)));
typedef float f32x16 __attribute__((ext_vector_type(16)));
typedef short bf16x8 __attribute__((ext_vector_type(8)));
typedef int   i32x2  __attribute__((ext_vector_type(2)));
typedef int   i32x4  __attribute__((ext_vector_type(4)));

#define SQ_SCALE 0.18033688011112042f   // 0.125 * log2(e)
#define MASK_B  (-1442695.040888963f)   // -1e6 * log2(e)
#define THR 10.0f

static __device__ __forceinline__ int cvt_pk(float lo, float hi) {
  int r;
  asm("v_cvt_pk_bf16_f32 %0, %1, %2" : "=v"(r) : "v"(lo), "v"(hi));
  return r;
}
static __device__ __forceinline__ float exp2v(float x) {
  float r;
  asm("v_exp_f32 %0, %1" : "=v"(r) : "v"(x));
  return r;
}
static __device__ __forceinline__ void swap32(int &a, int &b) {
  asm("v_permlane32_swap_b32 %0, %1" : "+v"(a), "+v"(b));
}

__global__ __launch_bounds__(256, 4)
void attn_fwd(const float* __restrict__ Qg, const float* __restrict__ Kg,
              const float* __restrict__ Vg, const int* __restrict__ Mg,
              float* __restrict__ Og) {
  // K tile: [32 keys][72 d] bf16; V^T tile: [64 d][40 keys] bf16; mask bias[32] f32
  __shared__ __align__(16) short Klds[2][32 * 72];
  __shared__ __align__(16) short Vtld[2][64 * 40];
  __shared__ __align__(16) float MB[2][32];

  const int t    = threadIdx.x;
  const int lane = t & 63;
  const int wid  = t >> 6;
  const int c    = lane & 31;   // q column (and d-row for V^T A-frag)
  const int hi   = lane >> 5;   // lane half

  // XCD-aware swizzle (bijective: 1024 = 8 XCDs x 128): the 16 q-blocks of
  // each bh land on one XCD -> K/V panel read once per XCD L2, not 8x.
  // Output-neutral: all addressing below derives from swz.
  const int bid  = (int)blockIdx.x;
  const int swz  = (bid & 7) * 128 + (bid >> 3);
  const int bh   = swz >> 4;                // 0..63
  const int qblk = (swz & 15) * 128;        // 128 q rows per block
  const int b    = bh >> 4;                 // batch (H=16)
  const size_t base = (size_t)bh * S_LEN * HD;
  const int qbase = qblk + wid * 32;        // this wave's 32 q rows

  // ---- Q fragment (B-operand of QK^T): lane holds Q[qbase+c][16s+8hi .. +7]
  bf16x8 qf[4];
#pragma unroll
  for (int s = 0; s < 4; ++s) {
    const float* qp = Qg + base + (size_t)(qbase + c) * HD + 16*s + 8*hi;
    float4 x0 = *(const float4*)qp;
    float4 x1 = *(const float4*)(qp + 4);
    i32x4 w;
    w[0] = cvt_pk(x0.x*SQ_SCALE, x0.y*SQ_SCALE);
    w[1] = cvt_pk(x0.z*SQ_SCALE, x0.w*SQ_SCALE);
    w[2] = cvt_pk(x1.x*SQ_SCALE, x1.y*SQ_SCALE);
    w[3] = cvt_pk(x1.z*SQ_SCALE, x1.w*SQ_SCALE);
    qf[s] = __builtin_bit_cast(bf16x8, w);
  }

  // ---- staging roles
  const int kkey = t & 31, kdg = t >> 5;   // K: (key, 8-d group)
  const int vd   = t & 63, vkg = t >> 6;   // V: (d, 4-key group)
  const float* kbase = Kg + base + (size_t)kkey * HD + 8*kdg;
  const float* vbase = Vg + base + vd + (size_t)(4*vkg) * HD;
  const int*   mbase = Mg + (size_t)b * S_LEN;

  float kr[8], vr[8]; float mbias = 0.f;

  auto LOADT = [&](int it) {
    const float* kp = kbase + (size_t)it * KVB * HD;
    *(float4*)&kr[0] = *(const float4*)kp;
    *(float4*)&kr[4] = *(const float4*)(kp + 4);
    const float* vp = vbase + (size_t)it * KVB * HD;
#pragma unroll
    for (int i = 0; i < 2; ++i)
#pragma unroll
      for (int j = 0; j < 4; ++j)
        vr[i*4+j] = vp[(16*i + j) * HD];
    if (t < 32) {
      int m = mbase[it * KVB + t];
      mbias = m ? 0.f : MASK_B;
    }
  };
  auto STORET = [&](int bf) {
    i32x4 kw;
    kw[0] = cvt_pk(kr[0], kr[1]); kw[1] = cvt_pk(kr[2], kr[3]);
    kw[2] = cvt_pk(kr[4], kr[5]); kw[3] = cvt_pk(kr[6], kr[7]);
    *(i32x4*)&Klds[bf][kkey*72 + 8*kdg] = kw;
    i32x2 va, vb;
    va[0] = cvt_pk(vr[0], vr[1]); va[1] = cvt_pk(vr[2], vr[3]);
    vb[0] = cvt_pk(vr[4], vr[5]); vb[1] = cvt_pk(vr[6], vr[7]);
    *(i32x2*)&Vtld[bf][vd*40 + 4*vkg]      = va;
    *(i32x2*)&Vtld[bf][vd*40 + 16 + 4*vkg] = vb;
    if (t < 32) MB[bf][t] = mbias;
  };

  f32x16 acc0 = {};  // O^T rows d=0..31
  f32x16 acc1 = {};  // O^T rows d=32..63
  float mrun = -1e30f, lrun = 0.f;

  LOADT(0); STORET(0); LOADT(1);
  __syncthreads();

  for (int it = 0; it < NT; ++it) {
    if (it + 1 < NT) STORET((it + 1) & 1);
    if (it + 2 < NT) LOADT(it + 2);
    const int cur = it & 1;

    // ---- S^T = K · Q^T  (rows=keys, cols=q)
    f32x16 S = {};
    __builtin_amdgcn_s_setprio(1);
#pragma unroll
    for (int s = 0; s < 4; ++s) {
      bf16x8 kf = *(const bf16x8*)&Klds[cur][c*72 + 16*s + 8*hi];
      S = __builtin_amdgcn_mfma_f32_32x32x16_bf16(kf, qf[s], S, 0, 0, 0);
    }
    __builtin_amdgcn_s_setprio(0);

    f32x4 bias4[4];
#pragma unroll
    for (int m = 0; m < 4; ++m)
      bias4[m] = *(const f32x4*)&MB[cur][8*m + 4*hi];

    // sb[r]: logit2 for key (r&3)+8*(r>>2)+4*hi, q=c
    float sb[16];
#pragma unroll
    for (int r = 0; r < 16; ++r)
      sb[r] = S[r] + bias4[r >> 2][r & 3];

    // row max over this tile's 32 keys
    float mx[8];
#pragma unroll
    for (int r = 0; r < 8; ++r) mx[r] = fmaxf(sb[r], sb[r+8]);
#pragma unroll
    for (int r = 0; r < 4; ++r) mx[r] = fmaxf(mx[r], mx[r+4]);
    float tmax = fmaxf(fmaxf(mx[0], mx[1]), fmaxf(mx[2], mx[3]));
    tmax = fmaxf(tmax, __shfl_xor(tmax, 32, 64));

    // defer-max: rescale only when the running max grows by > THR
    if (!__all(tmax <= mrun + THR)) {
      float mnew = fmaxf(mrun, tmax);
      float al = exp2v(mrun - mnew);
      acc0 *= al; acc1 *= al;
      lrun *= al; mrun = mnew;
    }

    // p = exp2(logit2 - m) (reuse sb)
#pragma unroll
    for (int r = 0; r < 16; ++r) sb[r] = exp2v(sb[r] - mrun);

    float sm[8];
#pragma unroll
    for (int r = 0; r < 8; ++r) sm[r] = sb[r] + sb[r+8];
#pragma unroll
    for (int r = 0; r < 4; ++r) sm[r] = sm[r] + sm[r+4];
    float rs = (sm[0] + sm[1]) + (sm[2] + sm[3]);
    rs += __shfl_xor(rs, 32, 64);
    lrun += rs;

    // pack P to bf16; permlane32_swap redistributes into B-fragment order
    int w[8];
#pragma unroll
    for (int m = 0; m < 8; ++m) w[m] = cvt_pk(sb[2*m], sb[2*m+1]);
    swap32(w[0], w[2]); swap32(w[1], w[3]);
    swap32(w[4], w[6]); swap32(w[5], w[7]);
    i32x4 pw0 = {w[0], w[1], w[2], w[3]};   // keys 0..15
    i32x4 pw1 = {w[4], w[5], w[6], w[7]};   // keys 16..31
    bf16x8 pb0 = __builtin_bit_cast(bf16x8, pw0);
    bf16x8 pb1 = __builtin_bit_cast(bf16x8, pw1);

    // ---- O^T += V^T · P^T
    {
      bf16x8 v00 = *(const bf16x8*)&Vtld[cur][(c     )*40      + 8*hi];
      bf16x8 v01 = *(const bf16x8*)&Vtld[cur][(c     )*40 + 16 + 8*hi];
      bf16x8 v10 = *(const bf16x8*)&Vtld[cur][(c + 32)*40      + 8*hi];
      bf16x8 v11 = *(const bf16x8*)&Vtld[cur][(c + 32)*40 + 16 + 8*hi];
      __builtin_amdgcn_s_setprio(1);
      acc0 = __builtin_amdgcn_mfma_f32_32x32x16_bf16(v00, pb0, acc0, 0, 0, 0);
      acc0 = __builtin_amdgcn_mfma_f32_32x32x16_bf16(v01, pb1, acc0, 0, 0, 0);
      acc1 = __builtin_amdgcn_mfma_f32_32x32x16_bf16(v10, pb0, acc1, 0, 0, 0);
      acc1 = __builtin_amdgcn_mfma_f32_32x32x16_bf16(v11, pb1, acc1, 0, 0, 0);
      __builtin_amdgcn_s_setprio(0);
    }

    __syncthreads();
  }

  // ---- epilogue: O[q][d] = O^T/l ; all lane-local, float4 stores
  const float linv = 1.0f / lrun;
  float* op = Og + base + (size_t)(qbase + c) * HD + 4*hi;
#pragma unroll
  for (int m = 0; m < 4; ++m) {
    f32x4 o0, o1;
#pragma unroll
    for (int j = 0; j < 4; ++j) {
      o0[j] = acc0[4*m + j] * linv;
      o1[j] = acc1[4*m + j] * linv;
    }
    *(f32x4*)(op + 8*m)      = o0;   // d = 8m+4hi .. +3
    *(f32x4*)(op + 32 + 8*m) = o1;   // d = 32+8m+4hi .. +3
  }
}

extern "C" void kernel_launch(void* const* d_in, const int* in_sizes, int n_in,
                              void* d_out, int out_size, void* d_ws, size_t ws_size,
                              hipStream_t stream) {
    const float* Q = (const float*)d_in[0];
    const float* K = (const float*)d_in[1];
    const float* V = (const float*)d_in[2];
    const int*   M = (const int*)d_in[3];
    float* O = (float*)d_out;
    dim3 grid(1024), block(256);
    hipLaunchKernelGGL(attn_fwd, grid, block, 0, stream, Q, K, V, M, O);
}

// Round 5
// 117.828 us; speedup vs baseline: 2.3763x; 1.0266x over previous
//
#include <hip/hip_runtime.h>

#define S_LEN 2048
#define HD 64
#define KVB 32
#define NT (S_LEN / KVB)   // 64 kv tiles

typedef float f32x4  __attribute__((ext_vector_type(4)));
typedef float f32x16 __attribute__((ext_vector_type(16)));
typedef short bf16x8 __attribute__((ext_vector_type(8)));
typedef int   i32x2  __attribute__((ext_vector_type(2)));
typedef int   i32x4  __attribute__((ext_vector_type(4)));

#define SQ_SCALE 0.18033688011112042f   // 0.125 * log2(e)
#define MASK_B  (-1442695.040888963f)   // -1e6 * log2(e)
#define THR 10.0f

static __device__ __forceinline__ int cvt_pk(float lo, float hi) {
  int r;
  asm("v_cvt_pk_bf16_f32 %0, %1, %2" : "=v"(r) : "v"(lo), "v"(hi));
  return r;
}
static __device__ __forceinline__ float exp2v(float x) {
  float r;
  asm("v_exp_f32 %0, %1" : "=v"(r) : "v"(x));
  return r;
}
static __device__ __forceinline__ void swap32(int &a, int &b) {
  asm("v_permlane32_swap_b32 %0, %1" : "+v"(a), "+v"(b));
}

__global__ __launch_bounds__(256, 4)
void attn_fwd(const float* __restrict__ Qg, const float* __restrict__ Kg,
              const float* __restrict__ Vg, const int* __restrict__ Mg,
              float* __restrict__ Og) {
  // 4-deep buffers: barrier once per 2 tiles -> waves can slip a full tile.
  // K tile: [32 keys][72 d] bf16; V^T tile: [64 d][40 keys] bf16; mask bias f32
  __shared__ __align__(16) short Klds[4][32 * 72];
  __shared__ __align__(16) short Vtld[4][64 * 40];
  __shared__ __align__(16) float MB[4][32];

  const int t    = threadIdx.x;
  const int lane = t & 63;
  const int wid  = t >> 6;
  const int c    = lane & 31;   // q column (and d-row for V^T A-frag)
  const int hi   = lane >> 5;   // lane half

  // XCD-aware swizzle (bijective: 1024 = 8 XCDs x 128): the 16 q-blocks of
  // each bh land on one XCD -> K/V panel read once per XCD L2, not 8x.
  const int bid  = (int)blockIdx.x;
  const int swz  = (bid & 7) * 128 + (bid >> 3);
  const int bh   = swz >> 4;                // 0..63
  const int qblk = (swz & 15) * 128;        // 128 q rows per block
  const int b    = bh >> 4;                 // batch (H=16)
  const size_t base = (size_t)bh * S_LEN * HD;
  const int qbase = qblk + wid * 32;        // this wave's 32 q rows

  // ---- Q fragment (B-operand of QK^T): lane holds Q[qbase+c][16s+8hi .. +7]
  bf16x8 qf[4];
#pragma unroll
  for (int s = 0; s < 4; ++s) {
    const float* qp = Qg + base + (size_t)(qbase + c) * HD + 16*s + 8*hi;
    float4 x0 = *(const float4*)qp;
    float4 x1 = *(const float4*)(qp + 4);
    i32x4 w;
    w[0] = cvt_pk(x0.x*SQ_SCALE, x0.y*SQ_SCALE);
    w[1] = cvt_pk(x0.z*SQ_SCALE, x0.w*SQ_SCALE);
    w[2] = cvt_pk(x1.x*SQ_SCALE, x1.y*SQ_SCALE);
    w[3] = cvt_pk(x1.z*SQ_SCALE, x1.w*SQ_SCALE);
    qf[s] = __builtin_bit_cast(bf16x8, w);
  }

  // ---- staging roles
  const int kkey = t & 31, kdg = t >> 5;   // K: (key, 8-d group)
  const int vd   = t & 63, vkg = t >> 6;   // V: (d, 4-key group)
  const float* kbase = Kg + base + (size_t)kkey * HD + 8*kdg;
  const float* vbase = Vg + base + vd + (size_t)(4*vkg) * HD;
  const int*   mbase = Mg + (size_t)b * S_LEN;

  float kr[8], vr[8]; float mbias = 0.f;

  auto LOADT = [&](int it) {
    const float* kp = kbase + (size_t)it * KVB * HD;
    *(float4*)&kr[0] = *(const float4*)kp;
    *(float4*)&kr[4] = *(const float4*)(kp + 4);
    const float* vp = vbase + (size_t)it * KVB * HD;
#pragma unroll
    for (int i = 0; i < 2; ++i)
#pragma unroll
      for (int j = 0; j < 4; ++j)
        vr[i*4+j] = vp[(16*i + j) * HD];
    if (t < 32) {
      int m = mbase[it * KVB + t];
      mbias = m ? 0.f : MASK_B;
    }
  };
  auto STORET = [&](int bf) {
    i32x4 kw;
    kw[0] = cvt_pk(kr[0], kr[1]); kw[1] = cvt_pk(kr[2], kr[3]);
    kw[2] = cvt_pk(kr[4], kr[5]); kw[3] = cvt_pk(kr[6], kr[7]);
    *(i32x4*)&Klds[bf][kkey*72 + 8*kdg] = kw;
    i32x2 va, vb;
    va[0] = cvt_pk(vr[0], vr[1]); va[1] = cvt_pk(vr[2], vr[3]);
    vb[0] = cvt_pk(vr[4], vr[5]); vb[1] = cvt_pk(vr[6], vr[7]);
    *(i32x2*)&Vtld[bf][vd*40 + 4*vkg]      = va;
    *(i32x2*)&Vtld[bf][vd*40 + 16 + 4*vkg] = vb;
    if (t < 32) MB[bf][t] = mbias;
  };

  f32x16 acc0 = {};  // O^T rows d=0..31
  f32x16 acc1 = {};  // O^T rows d=32..63
  float mrun = -1e30f;
  float lrun = 0.f;  // per-lane partial row-sum (this hi-half's keys);
                     // merged across hi at epilogue. Rescale factor al is
                     // hi-uniform (tmax is shfl-merged) so partials scale right.

  auto COMPUTE = [&](int cur) {
    // ---- S^T = K · Q^T  (rows=keys, cols=q)
    f32x16 S = {};
    __builtin_amdgcn_s_setprio(1);
#pragma unroll
    for (int s = 0; s < 4; ++s) {
      bf16x8 kf = *(const bf16x8*)&Klds[cur][c*72 + 16*s + 8*hi];
      S = __builtin_amdgcn_mfma_f32_32x32x16_bf16(kf, qf[s], S, 0, 0, 0);
    }
    __builtin_amdgcn_s_setprio(0);

    f32x4 bias4[4];
#pragma unroll
    for (int m = 0; m < 4; ++m)
      bias4[m] = *(const f32x4*)&MB[cur][8*m + 4*hi];

    // sb[r]: logit2 for key (r&3)+8*(r>>2)+4*hi, q=c
    float sb[16];
#pragma unroll
    for (int r = 0; r < 16; ++r)
      sb[r] = S[r] + bias4[r >> 2][r & 3];

    // row max over this tile's 32 keys
    float mx[8];
#pragma unroll
    for (int r = 0; r < 8; ++r) mx[r] = fmaxf(sb[r], sb[r+8]);
#pragma unroll
    for (int r = 0; r < 4; ++r) mx[r] = fmaxf(mx[r], mx[r+4]);
    float tmax = fmaxf(fmaxf(mx[0], mx[1]), fmaxf(mx[2], mx[3]));
    tmax = fmaxf(tmax, __shfl_xor(tmax, 32, 64));

    // defer-max: rescale only when the running max grows by > THR
    if (!__all(tmax <= mrun + THR)) {
      float mnew = fmaxf(mrun, tmax);
      float al = exp2v(mrun - mnew);
      acc0 *= al; acc1 *= al;
      lrun *= al; mrun = mnew;
    }

    // hoist V fragments
    bf16x8 v00 = *(const bf16x8*)&Vtld[cur][(c     )*40      + 8*hi];
    bf16x8 v01 = *(const bf16x8*)&Vtld[cur][(c     )*40 + 16 + 8*hi];
    bf16x8 v10 = *(const bf16x8*)&Vtld[cur][(c + 32)*40      + 8*hi];
    bf16x8 v11 = *(const bf16x8*)&Vtld[cur][(c + 32)*40 + 16 + 8*hi];

    // ---- half 0: keys 0..15 -> pb0 -> 2 PV MFMAs (overlap with half-1 exp)
    float p0[8];
#pragma unroll
    for (int r = 0; r < 8; ++r) p0[r] = exp2v(sb[r] - mrun);
    int w0 = cvt_pk(p0[0], p0[1]), w1 = cvt_pk(p0[2], p0[3]);
    int w2 = cvt_pk(p0[4], p0[5]), w3 = cvt_pk(p0[6], p0[7]);
    swap32(w0, w2); swap32(w1, w3);
    i32x4 pw0 = {w0, w1, w2, w3};
    bf16x8 pb0 = __builtin_bit_cast(bf16x8, pw0);
    __builtin_amdgcn_s_setprio(1);
    acc0 = __builtin_amdgcn_mfma_f32_32x32x16_bf16(v00, pb0, acc0, 0, 0, 0);
    acc1 = __builtin_amdgcn_mfma_f32_32x32x16_bf16(v10, pb0, acc1, 0, 0, 0);
    __builtin_amdgcn_s_setprio(0);

    // ---- half 1: keys 16..31 -> pb1 -> 2 PV MFMAs
    float p1[8];
#pragma unroll
    for (int r = 0; r < 8; ++r) p1[r] = exp2v(sb[8 + r] - mrun);
    int w4 = cvt_pk(p1[0], p1[1]), w5 = cvt_pk(p1[2], p1[3]);
    int w6 = cvt_pk(p1[4], p1[5]), w7 = cvt_pk(p1[6], p1[7]);
    swap32(w4, w6); swap32(w5, w7);
    i32x4 pw1 = {w4, w5, w6, w7};
    bf16x8 pb1 = __builtin_bit_cast(bf16x8, pw1);
    __builtin_amdgcn_s_setprio(1);
    acc0 = __builtin_amdgcn_mfma_f32_32x32x16_bf16(v01, pb1, acc0, 0, 0, 0);
    acc1 = __builtin_amdgcn_mfma_f32_32x32x16_bf16(v11, pb1, acc1, 0, 0, 0);
    __builtin_amdgcn_s_setprio(0);

    // per-lane partial row-sum (no per-tile shfl)
    float s0 = ((p0[0]+p0[1]) + (p0[2]+p0[3])) + ((p0[4]+p0[5]) + (p0[6]+p0[7]));
    float s1 = ((p1[0]+p1[1]) + (p1[2]+p1[3])) + ((p1[4]+p1[5]) + (p1[6]+p1[7]));
    lrun += s0 + s1;
  };

  // ---- prologue: stage tiles 0,1; tile 2 in flight
  LOADT(0); STORET(0);
  LOADT(1); STORET(1);
  LOADT(2);
  __syncthreads();

  for (int it = 0; it < NT; it += 2) {
    // A: tile it
    if (it + 2 < NT) STORET((it + 2) & 3);
    if (it + 3 < NT) LOADT(it + 3);
    COMPUTE(it & 3);
    // B: tile it+1
    if (it + 3 < NT) STORET((it + 3) & 3);
    if (it + 4 < NT) LOADT(it + 4);
    COMPUTE((it + 1) & 3);
    __syncthreads();
  }

  // ---- epilogue: merge partial l across hi halves; normalize; store fp32
  float lfull = lrun + __shfl_xor(lrun, 32, 64);
  const float linv = 1.0f / lfull;
  float* op = Og + base + (size_t)(qbase + c) * HD + 4*hi;
#pragma unroll
  for (int m = 0; m < 4; ++m) {
    f32x4 o0, o1;
#pragma unroll
    for (int j = 0; j < 4; ++j) {
      o0[j] = acc0[4*m + j] * linv;
      o1[j] = acc1[4*m + j] * linv;
    }
    *(f32x4*)(op + 8*m)      = o0;   // d = 8m+4hi .. +3
    *(f32x4*)(op + 32 + 8*m) = o1;   // d = 32+8m+4hi .. +3
  }
}

extern "C" void kernel_launch(void* const* d_in, const int* in_sizes, int n_in,
                              void* d_out, int out_size, void* d_ws, size_t ws_size,
                              hipStream_t stream) {
    const float* Q = (const float*)d_in[0];
    const float* K = (const float*)d_in[1];
    const float* V = (const float*)d_in[2];
    const int*   M = (const int*)d_in[3];
    float* O = (float*)d_out;
    dim3 grid(1024), block(256);
    hipLaunchKernelGGL(attn_fwd, grid, block, 0, stream, Q, K, V, M, O);
}